// Round 4
// baseline (262.086 us; speedup 1.0000x reference)
//
#include <hip/hip_runtime.h>
#include <hip/hip_bf16.h>

#define D 64
#define BSHIFT 8           // 256 nodes per bucket
#define BNODES 256
#define BCAP 4096          // edge capacity per bucket region (exp 2558, +30 sigma)
#define PTILE 2048         // edges per partition tile (489 blocks -> full CU coverage)

typedef __attribute__((ext_vector_type(8))) short short8;
typedef __attribute__((ext_vector_type(4))) float float4v;

// flags[0] = 1 if float tensors are fp32 (else bf16)
// flags[1] = 1 if edge_index is int64 (else int32)

__device__ __forceinline__ float bf16u_to_f32(unsigned short u) {
  union { unsigned int i; float f; } c;
  c.i = ((unsigned int)u) << 16;
  return c.f;
}

__device__ __forceinline__ unsigned short f32_to_bf16u(float f) {
  union { float f; unsigned int u; } c;
  c.f = f;
  unsigned int r = (c.u + 0x7fffu + ((c.u >> 16) & 1u)) >> 16;  // RNE
  return (unsigned short)r;
}

// ---------------- probe dtypes ----------------

__global__ void k_probe(const void* W, const void* ei, int* flags) {
  int lane = threadIdx.x & 63;
  const unsigned short* wb = (const unsigned short*)W;
  bool big = false;
  for (int i = lane; i < 512; i += 64) {
    float v = bf16u_to_f32(wb[i]);
    if (!(fabsf(v) < 100.f)) big = true;  // NaN lands here too
  }
  int anybig = __any(big);
  const int* e32 = (const int*)ei;
  bool nz = (e32[2 * lane + 1] != 0);  // odd words of first 64 pairs
  int anynz = __any(nz);
  if (threadIdx.x == 0) {
    flags[0] = anybig ? 1 : 0;  // huge magnitudes => data is actually fp32
    flags[1] = anynz ? 0 : 1;   // all-zero odd words => int64
  }
}

// ---------------- weight prep + cursor init (parallel) ----------------

__global__ __launch_bounds__(256) void k_prep(
    const void* __restrict__ Ws, const void* __restrict__ Wout,
    const void* __restrict__ bs, const void* __restrict__ bout,
    const int* __restrict__ flags, unsigned short* __restrict__ WT,
    float* __restrict__ biasf, int* __restrict__ bucket_cursor) {
  int f32 = flags[0];
  int gid = blockIdx.x * 256 + threadIdx.x;
  int stride = gridDim.x * 256;

  for (int i = gid; i < 512; i += stride) bucket_cursor[i] = i * BCAP;

  // transpose 4 weight matrices into WT[l][n][k] (bf16)
  for (int i = gid; i < 4 * 4096; i += stride) {
    int l = i >> 12;
    int r = i & 4095;
    int k = r >> 6;
    int nn = r & 63;
    unsigned short v;
    if (l < 3) {
      v = f32 ? f32_to_bf16u(((const float*)Ws)[l * 4096 + r])
              : ((const unsigned short*)Ws)[l * 4096 + r];
    } else {
      v = f32 ? f32_to_bf16u(((const float*)Wout)[r])
              : ((const unsigned short*)Wout)[r];
    }
    WT[l * 4096 + nn * 64 + k] = v;
  }
  // biases -> fp32
  for (int i = gid; i < 4 * 64; i += stride) {
    int l = i >> 6;
    int j = i & 63;
    float v;
    if (l < 3)
      v = f32 ? ((const float*)bs)[l * 64 + j]
              : bf16u_to_f32(((const unsigned short*)bs)[l * 64 + j]);
    else
      v = f32 ? ((const float*)bout)[j]
              : bf16u_to_f32(((const unsigned short*)bout)[j]);
    biasf[i] = v;
  }
}

// ---------------- bucketed partition (fixed-capacity regions) ----------------

__global__ __launch_bounds__(256) void k_partition(
    const void* __restrict__ ei, const int* __restrict__ flags,
    int* __restrict__ bucket_cursor, int* __restrict__ packed, int e) {
  __shared__ int lhist[512];
  __shared__ int lbase[512];
  int tid = threadIdx.x;
  int t0 = blockIdx.x * PTILE;
  int tend = min(t0 + PTILE, e);
  if (t0 >= e) return;
  int i64 = flags[1];

  for (int b = tid; b < 512; b += 256) lhist[b] = 0;
  __syncthreads();

  if (i64) {
    const long long* dst = (const long long*)ei + e;
    for (int i = t0 + tid; i < tend; i += 256)
      atomicAdd(&lhist[((int)dst[i]) >> BSHIFT], 1);
  } else {
    const int* dst = (const int*)ei + e;
    for (int i = t0 + tid; i < tend; i += 256)
      atomicAdd(&lhist[dst[i] >> BSHIFT], 1);
  }
  __syncthreads();

  for (int b = tid; b < 512; b += 256) {
    int c = lhist[b];
    lbase[b] = c ? atomicAdd(&bucket_cursor[b], c) : 0;
    lhist[b] = 0;  // reuse as rank counter
  }
  __syncthreads();

  if (i64) {
    const long long* srcp = (const long long*)ei;
    const long long* dstp = srcp + e;
    for (int i = t0 + tid; i < tend; i += 256) {
      int s = (int)srcp[i];
      int d = (int)dstp[i];
      int b = d >> BSHIFT;
      int r = atomicAdd(&lhist[b], 1);
      packed[lbase[b] + r] = (s << BSHIFT) | (d & (BNODES - 1));
    }
  } else {
    const int* srcp = (const int*)ei;
    const int* dstp = srcp + e;
    for (int i = t0 + tid; i < tend; i += 256) {
      int s = srcp[i];
      int d = dstp[i];
      int b = d >> BSHIFT;
      int r = atomicAdd(&lhist[b], 1);
      packed[lbase[b] + r] = (s << BSHIFT) | (d & (BNODES - 1));
    }
  }
}

// One block per bucket: LDS counting sort -> per-node src list (grouped by
// dst) in the bucket's csr region, rowrange (beg,end), dinv.
__global__ __launch_bounds__(256) void k_sort_csr(
    const int* __restrict__ packed, const int* __restrict__ bucket_cursor,
    int* __restrict__ csr, int2* __restrict__ rowrange,
    float* __restrict__ dinv, int n) {
  __shared__ int lcnt[BNODES];
  __shared__ int lofs[BNODES];
  __shared__ int sbuf[BNODES];
  int tid = threadIdx.x;
  int bucket = blockIdx.x;
  int node0 = bucket << BSHIFT;
  int nodes = min(BNODES, n - node0);
  int s0 = bucket * BCAP;
  int s1 = bucket_cursor[bucket];  // region end after partition
  lcnt[tid] = 0;
  __syncthreads();
  for (int i = s0 + tid; i < s1; i += 256)
    atomicAdd(&lcnt[packed[i] & (BNODES - 1)], 1);
  __syncthreads();
  int v = lcnt[tid];
  sbuf[tid] = v;
  __syncthreads();
  for (int off = 1; off < BNODES; off <<= 1) {
    int tv = (tid >= off) ? sbuf[tid - off] : 0;
    __syncthreads();
    sbuf[tid] += tv;
    __syncthreads();
  }
  int excl = sbuf[tid] - v;
  lofs[tid] = excl;
  lcnt[tid] = 0;  // reuse as rank counter
  if (tid < nodes) {
    rowrange[node0 + tid] = make_int2(s0 + excl, s0 + excl + v);
    dinv[node0 + tid] = rsqrtf((float)(v + 1));  // +1 = self loop
  }
  __syncthreads();
  for (int i = s0 + tid; i < s1; i += 256) {
    int pk = packed[i];
    int ld = pk & (BNODES - 1);
    int r = atomicAdd(&lcnt[ld], 1);
    csr[s0 + lofs[ld] + r] = pk >> BSHIFT;
  }
}

// ---------------- z0 = dinv * x0 (bf16), handles fp32/bf16 input ----------------

__global__ __launch_bounds__(256) void k_scale(
    const void* __restrict__ x0, const int* __restrict__ flags,
    const float* __restrict__ dinv, ushort4* __restrict__ z, int n16) {
  int f32 = flags[0];
  int i = blockIdx.x * 256 + threadIdx.x;
  int stride = gridDim.x * 256;
  for (; i < n16; i += stride) {
    float d = dinv[i >> 4];
    ushort4 o;
    if (f32) {
      float4 v = ((const float4*)x0)[i];
      o.x = f32_to_bf16u(d * v.x);
      o.y = f32_to_bf16u(d * v.y);
      o.z = f32_to_bf16u(d * v.z);
      o.w = f32_to_bf16u(d * v.w);
    } else {
      ushort4 v = ((const ushort4*)x0)[i];
      o.x = f32_to_bf16u(d * bf16u_to_f32(v.x));
      o.y = f32_to_bf16u(d * bf16u_to_f32(v.y));
      o.z = f32_to_bf16u(d * bf16u_to_f32(v.z));
      o.w = f32_to_bf16u(d * bf16u_to_f32(v.w));
    }
    z[i] = o;
  }
}

// ---------------- fused layer ----------------
// y = dinv_dst*(z_dst + sum z_src); out = relu(yW+b) [optionally * dinv].
// Round-4: PERSISTENT blocks + inter-tile pipeline. Ladder so far:
//   r0 48-52us: per-tile blocks, 2700 addr/wave        (addr-bound theory)
//   r3 ~41us:   addr cut to ~900/wave (16B gathers, packed idx table) -> +15%
//   => residual is LATENCY CHAINS: each short-lived block serially does
//      rowrange -> shfl -> csr -> shfl -> gather (~1us) before any compute,
//      re-loads W-frags, then drains at the barrier. 6250 blocks pay this.
// Fix: grid = 1024 persistent blocks (4/CU at the (256,4) VGPR cap), each
// striding tiles. Next tile's rowrange issues at iteration top (hides under
// gathers); next tile's csr index-table load issues after accumulate (hides
// under tail/merge/MFMA/stores); ybf double-buffered so ONE barrier/tile;
// W-frags + bias loaded once per block. Wave-uniform deg-skip drops the
// hi-slot gather when deg<8 (~22% of nodes). Spill tripwire: WRITE_SIZE
// must stay ~12.5 MB.
__global__ __launch_bounds__(256, 4) void k_fused(
    const unsigned short* __restrict__ z, const int2* __restrict__ rowrange,
    const int* __restrict__ csr, const float* __restrict__ dinv,
    const unsigned short* __restrict__ WT, const float* __restrict__ biasf,
    unsigned short* __restrict__ out, int n, int scale_out, int ntiles) {
  __shared__ unsigned short ybf[2][16 * 80];
  const int tid = threadIdx.x;
  const int lane = tid & 63;
  const int w = tid >> 6;   // wave id = output col-tile
  const int q = lane >> 4;  // phase-2 quarter
  const int f = lane & 15;  // phase-2 frag row
  const int h = lane & 7;   // 16B slot within a 128B z row
  const int g8 = lane >> 3; // 8-lane group = edge slot group
  const int jx = lane >> 4; // index-table node
  const int m = lane & 15;  // index-table slot

  // B-frags + bias for this wave's column tile (once per persistent block)
  short8 b0 = *(const short8*)(WT + (size_t)(f + 16 * w) * 64 + q * 8);
  short8 b1 = *(const short8*)(WT + (size_t)(f + 16 * w) * 64 + 32 + q * 8);
  const float bv = biasf[16 * w + f];

  const short8* z8 = (const short8*)z;
  const int NB = gridDim.x;
  if ((int)blockIdx.x >= ntiles) return;

  // decode one rowrange word-vector into ranges/degrees + load the packed
  // index table entry (slot 0 = self, slots 1..15 = first 15 csr edges)
  auto decode = [&](int rrw_v, int bn, int& rx0, int& rx1, int& rx2, int& rx3,
                    int& d0, int& d1, int& d2, int& d3) -> int {
    rx0 = __shfl(rrw_v, 0, 64);
    int ry0 = __shfl(rrw_v, 1, 64);
    rx1 = __shfl(rrw_v, 2, 64);
    int ry1 = __shfl(rrw_v, 3, 64);
    rx2 = __shfl(rrw_v, 4, 64);
    int ry2 = __shfl(rrw_v, 5, 64);
    rx3 = __shfl(rrw_v, 6, 64);
    int ry3 = __shfl(rrw_v, 7, 64);
    d0 = ry0 - rx0;
    d1 = ry1 - rx1;
    d2 = ry2 - rx2;
    d3 = ry3 - rx3;
    int rxj = (jx & 2) ? ((jx & 1) ? rx3 : rx2) : ((jx & 1) ? rx1 : rx0);
    int dgj = (jx & 2) ? ((jx & 1) ? d3 : d2) : ((jx & 1) ? d1 : d0);
    int coff = (m >= 1 && m <= dgj) ? (m - 1) : 0;
    int idxv = csr[rxj + coff];
    if (m == 0) idxv = bn + jx;
    return idxv;
  };

  // prologue: tile blockIdx.x
  int rrw = 0;
  if (lane < 8)
    rrw = ((const int*)rowrange)[((size_t)blockIdx.x * 16 + w * 4) * 2 + lane];
  int rx0, rx1, rx2, rx3, d0, d1, d2, d3;
  int idx = decode(rrw, blockIdx.x * 16 + w * 4, rx0, rx1, rx2, rx3, d0, d1,
                   d2, d3);
  int pp = 0;

  for (int t = blockIdx.x; t < ntiles; t += NB) {
    const int tn = t + NB;
    const int row0 = t * 16;
    const int base_node = row0 + w * 4;

    // prefetch next tile's rowrange (latency hides under gathers)
    int rrw_n = 0;
    if (lane < 8 && tn < ntiles)
      rrw_n = ((const int*)rowrange)[((size_t)tn * 16 + w * 4) * 2 + lane];

    // --- gathers: 8 instrs max, 8 edges each (16B/lane, 8 lanes/row) ---
    short8 g[8];
#pragma unroll
    for (int t8 = 0; t8 < 8; t8++) {
      const int j = t8 >> 1;
      const int hi = t8 & 1;
      int dg = (j == 0) ? d0 : (j == 1) ? d1 : (j == 2) ? d2 : d3;
      if (hi && dg < 8) continue;  // wave-uniform skip
      int u = (hi << 3) + g8;
      int s = __shfl(idx, (j << 4) + u, 64);
      g[t8] = z8[(size_t)s * 8 + h];
    }

    float a0[8] = {0, 0, 0, 0, 0, 0, 0, 0};
    float a1[8] = {0, 0, 0, 0, 0, 0, 0, 0};
    float a2[8] = {0, 0, 0, 0, 0, 0, 0, 0};
    float a3[8] = {0, 0, 0, 0, 0, 0, 0, 0};
#pragma unroll
    for (int t8 = 0; t8 < 8; t8++) {
      const int j = t8 >> 1;
      const int hi = t8 & 1;
      int dg = (j == 0) ? d0 : (j == 1) ? d1 : (j == 2) ? d2 : d3;
      if (hi && dg < 8) continue;
      int u = (hi << 3) + g8;
      float vm = (u <= dg) ? 1.f : 0.f;
      float* aj = (j == 0) ? a0 : (j == 1) ? a1 : (j == 2) ? a2 : a3;
#pragma unroll
      for (int c = 0; c < 8; c++)
        aj[c] += vm * bf16u_to_f32((unsigned short)g[t8][c]);
    }

    // prefetch next tile's index table (csr load hides under merge/phase 2)
    int nrx0 = 0, nrx1 = 0, nrx2 = 0, nrx3 = 0;
    int nd0 = 0, nd1 = 0, nd2 = 0, nd3 = 0, idx_n = 0;
    if (tn < ntiles)
      idx_n = decode(rrw_n, tn * 16 + w * 4, nrx0, nrx1, nrx2, nrx3, nd0, nd1,
                     nd2, nd3);

    // --- rare tail: deg > 15, 8 edges per round ---
#pragma unroll
    for (int j = 0; j < 4; j++) {
      int rx = (j == 0) ? rx0 : (j == 1) ? rx1 : (j == 2) ? rx2 : rx3;
      int dg = (j == 0) ? d0 : (j == 1) ? d1 : (j == 2) ? d2 : d3;
      float* aj = (j == 0) ? a0 : (j == 1) ? a1 : (j == 2) ? a2 : a3;
      for (int e0 = 15; e0 < dg; e0 += 8) {
        int e = e0 + g8;
        bool vv = e < dg;
        int s = csr[rx + (vv ? e : 0)];
        short8 tv = z8[(size_t)s * 8 + h];
        float vm = vv ? 1.f : 0.f;
#pragma unroll
        for (int c = 0; c < 8; c++)
          aj[c] += vm * bf16u_to_f32((unsigned short)tv[c]);
      }
    }

    // --- merge the 8 groups (butterfly over lane bits 3,4,5) ---
#pragma unroll
    for (int c = 0; c < 8; c++) {
      a0[c] += __shfl_xor(a0[c], 8, 64);
      a1[c] += __shfl_xor(a1[c], 8, 64);
      a2[c] += __shfl_xor(a2[c], 8, 64);
      a3[c] += __shfl_xor(a3[c], 8, 64);
      a0[c] += __shfl_xor(a0[c], 16, 64);
      a1[c] += __shfl_xor(a1[c], 16, 64);
      a2[c] += __shfl_xor(a2[c], 16, 64);
      a3[c] += __shfl_xor(a3[c], 16, 64);
      a0[c] += __shfl_xor(a0[c], 32, 64);
      a1[c] += __shfl_xor(a1[c], 32, 64);
      a2[c] += __shfl_xor(a2[c], 32, 64);
      a3[c] += __shfl_xor(a3[c], 32, 64);
    }

    // --- lanes 0..31: scale by dinv_dst, pack, write y rows (16B each) ---
    if (lane < 32) {
      int jw = lane >> 3;  // node within wave
      float dv = dinv[base_node + jw];
      unsigned int pk[4];
#pragma unroll
      for (int cp = 0; cp < 4; cp++) {
        float vlo = (jw & 2) ? ((jw & 1) ? a3[2 * cp] : a2[2 * cp])
                             : ((jw & 1) ? a1[2 * cp] : a0[2 * cp]);
        float vhi = (jw & 2) ? ((jw & 1) ? a3[2 * cp + 1] : a2[2 * cp + 1])
                             : ((jw & 1) ? a1[2 * cp + 1] : a0[2 * cp + 1]);
        unsigned int lo = f32_to_bf16u(dv * vlo);
        unsigned int hi = f32_to_bf16u(dv * vhi);
        pk[cp] = lo | (hi << 16);
      }
      *(uint4*)&ybf[pp][(w * 4 + jw) * 80 + 8 * h] =
          make_uint4(pk[0], pk[1], pk[2], pk[3]);
    }
    __syncthreads();

    // --- phase 2: MFMA yW for this wave's 16 columns ---
    short8 fa0 = *(const short8*)&ybf[pp][f * 80 + q * 8];
    short8 fa1 = *(const short8*)&ybf[pp][f * 80 + 32 + q * 8];
    float4v zz = {0.f, 0.f, 0.f, 0.f};
    float4v acc = __builtin_amdgcn_mfma_f32_16x16x32_bf16(fa0, b0, zz, 0, 0, 0);
    acc = __builtin_amdgcn_mfma_f32_16x16x32_bf16(fa1, b1, acc, 0, 0, 0);

    if (scale_out) {
      float4 dv4 = *(const float4*)(dinv + row0 + q * 4);
      float dvr[4] = {dv4.x, dv4.y, dv4.z, dv4.w};
#pragma unroll
      for (int reg = 0; reg < 4; reg++) {
        int row = row0 + q * 4 + reg;
        if (row < n)
          out[(size_t)row * 64 + 16 * w + f] =
              f32_to_bf16u(dvr[reg] * fmaxf(acc[reg] + bv, 0.f));
      }
    } else {
#pragma unroll
      for (int reg = 0; reg < 4; reg++) {
        int row = row0 + q * 4 + reg;
        if (row < n)
          out[(size_t)row * 64 + 16 * w + f] =
              f32_to_bf16u(fmaxf(acc[reg] + bv, 0.f));
      }
    }

    // rotate pipeline state
    rx0 = nrx0; rx1 = nrx1; rx2 = nrx2; rx3 = nrx3;
    d0 = nd0; d1 = nd1; d2 = nd2; d3 = nd3;
    idx = idx_n;
    pp ^= 1;
  }
}

// ---------------- final projection GEMM ----------------
// out[N,64] = x @ Wout + bias; x bf16; store dtype per flags[0].
__global__ __launch_bounds__(256) void k_gemm_final(
    const unsigned short* __restrict__ xin,
    const unsigned short* __restrict__ WT, const float* __restrict__ bias,
    void* __restrict__ out, const int* __restrict__ flags, int ntiles) {
  int lane = threadIdx.x & 63;
  int wid = threadIdx.x >> 6;
  int f = lane & 15;
  int q = lane >> 4;

  short8 bfr[4][2];
#pragma unroll
  for (int ct = 0; ct < 4; ct++)
#pragma unroll
    for (int kt = 0; kt < 2; kt++)
      bfr[ct][kt] =
          *(const short8*)(WT + (size_t)(f + 16 * ct) * 64 + kt * 32 + q * 8);

  int wave = blockIdx.x * 4 + wid;
  int nwaves = gridDim.x * 4;
  for (int t = wave; t < ntiles; t += nwaves) {
    int row0 = t * 16;
    const unsigned short* xr = xin + (size_t)(row0 + f) * 64 + q * 8;
    short8 a0 = *(const short8*)(xr);
    short8 a1 = *(const short8*)(xr + 32);
    float4v acc[4];
#pragma unroll
    for (int ct = 0; ct < 4; ct++) {
      float4v z = {0.f, 0.f, 0.f, 0.f};
      acc[ct] =
          __builtin_amdgcn_mfma_f32_16x16x32_bf16(a0, bfr[ct][0], z, 0, 0, 0);
      acc[ct] = __builtin_amdgcn_mfma_f32_16x16x32_bf16(a1, bfr[ct][1],
                                                        acc[ct], 0, 0, 0);
    }
    int f32o = flags[0];
    float bv[4];
#pragma unroll
    for (int ct = 0; ct < 4; ct++) bv[ct] = bias[f + 16 * ct];
    if (f32o) {
      float* op = (float*)out;
#pragma unroll
      for (int reg = 0; reg < 4; reg++) {
        size_t rb = (size_t)(row0 + q * 4 + reg) * 64 + f;
#pragma unroll
        for (int ct = 0; ct < 4; ct++) op[rb + 16 * ct] = acc[ct][reg] + bv[ct];
      }
    } else {
      unsigned short* op = (unsigned short*)out;
#pragma unroll
      for (int reg = 0; reg < 4; reg++) {
        size_t rb = (size_t)(row0 + q * 4 + reg) * 64 + f;
#pragma unroll
        for (int ct = 0; ct < 4; ct++)
          op[rb + 16 * ct] = f32_to_bf16u(acc[ct][reg] + bv[ct]);
      }
    }
  }
}

// ---------------- launch ----------------

extern "C" void kernel_launch(void* const* d_in, const int* in_sizes, int n_in,
                              void* d_out, int out_size, void* d_ws,
                              size_t ws_size, hipStream_t stream) {
  const void* x0 = d_in[0];
  const void* ei = d_in[1];
  const void* Ws = d_in[2];
  const void* bs = d_in[3];
  const void* Wout = d_in[4];
  const void* bout = d_in[5];

  const int N = in_sizes[0] / D;  // 100000
  const int E = in_sizes[1] / 2;  // 1000000
  const int NBUC = (N + BNODES - 1) >> BSHIFT;  // 391
  const int NT = (N + 15) / 16;  // 6250 row tiles

  char* p = (char*)d_ws;
  auto alloc = [&](size_t bytes) {
    char* r = p;
    p += (bytes + 511) & ~(size_t)511;
    return r;
  };
  int* flags = (int*)alloc(8);
  int* bucket_cursor = (int*)alloc(512 * 4);
  int* packed = (int*)alloc((size_t)512 * BCAP * 4);
  int* csr = (int*)alloc((size_t)512 * BCAP * 4);
  int2* rowrange = (int2*)alloc((size_t)N * 8);
  float* dinv = (float*)alloc((size_t)N * 4);
  unsigned short* WT = (unsigned short*)alloc(4 * 4096 * 2);
  float* biasf = (float*)alloc(4 * 64 * 4);
  unsigned short* za = (unsigned short*)alloc((size_t)N * D * 2);
  unsigned short* zb = (unsigned short*)alloc((size_t)N * D * 2);
  (void)ws_size;
  (void)n_in;
  (void)out_size;

  k_probe<<<1, 64, 0, stream>>>(Ws, ei, flags);
  k_prep<<<32, 256, 0, stream>>>(Ws, Wout, bs, bout, flags, WT, biasf,
                                 bucket_cursor);
  int ptiles = (E + PTILE - 1) / PTILE;
  k_partition<<<ptiles, 256, 0, stream>>>(ei, flags, bucket_cursor, packed, E);
  k_sort_csr<<<NBUC, 256, 0, stream>>>(packed, bucket_cursor, csr, rowrange,
                                       dinv, N);
  k_scale<<<1024, 256, 0, stream>>>(x0, flags, dinv, (ushort4*)za, N * 16);

  const int FGRID = 1024;  // 4 persistent blocks per CU
  // layer 0: za -> zb (z'), layer 1: zb -> za (z'), layer 2: za -> zb (x3)
  k_fused<<<FGRID, 256, 0, stream>>>(za, rowrange, csr, dinv, WT + 0 * 4096,
                                     biasf + 0 * 64, zb, N, 1, NT);
  k_fused<<<FGRID, 256, 0, stream>>>(zb, rowrange, csr, dinv, WT + 1 * 4096,
                                     biasf + 1 * 64, za, N, 1, NT);
  k_fused<<<FGRID, 256, 0, stream>>>(za, rowrange, csr, dinv, WT + 2 * 4096,
                                     biasf + 2 * 64, zb, N, 0, NT);
  k_gemm_final<<<(NT + 3) / 4, 256, 0, stream>>>(zb, WT + 3 * 4096,
                                                 biasf + 3 * 64, d_out, flags,
                                                 NT);
}

// Round 5
// 259.009 us; speedup vs baseline: 1.0119x; 1.0119x over previous
//
#include <hip/hip_runtime.h>
#include <hip/hip_bf16.h>

#define D 64
#define BSHIFT 8           // 256 nodes per bucket
#define BNODES 256
#define BCAP 4096          // edge capacity per bucket region (exp 2558, +30 sigma)
#define PTILE 2048         // edges per partition tile (489 blocks -> full CU coverage)

typedef __attribute__((ext_vector_type(8))) short short8;
typedef __attribute__((ext_vector_type(4))) float float4v;

// flags[0] = 1 if float tensors are fp32 (else bf16)
// flags[1] = 1 if edge_index is int64 (else int32)

__device__ __forceinline__ float bf16u_to_f32(unsigned short u) {
  union { unsigned int i; float f; } c;
  c.i = ((unsigned int)u) << 16;
  return c.f;
}

__device__ __forceinline__ unsigned short f32_to_bf16u(float f) {
  union { float f; unsigned int u; } c;
  c.f = f;
  unsigned int r = (c.u + 0x7fffu + ((c.u >> 16) & 1u)) >> 16;  // RNE
  return (unsigned short)r;
}

// ---------------- probe dtypes ----------------

__global__ void k_probe(const void* W, const void* ei, int* flags) {
  int lane = threadIdx.x & 63;
  const unsigned short* wb = (const unsigned short*)W;
  bool big = false;
  for (int i = lane; i < 512; i += 64) {
    float v = bf16u_to_f32(wb[i]);
    if (!(fabsf(v) < 100.f)) big = true;  // NaN lands here too
  }
  int anybig = __any(big);
  const int* e32 = (const int*)ei;
  bool nz = (e32[2 * lane + 1] != 0);  // odd words of first 64 pairs
  int anynz = __any(nz);
  if (threadIdx.x == 0) {
    flags[0] = anybig ? 1 : 0;  // huge magnitudes => data is actually fp32
    flags[1] = anynz ? 0 : 1;   // all-zero odd words => int64
  }
}

// ---------------- weight prep + cursor init (parallel) ----------------

__global__ __launch_bounds__(256) void k_prep(
    const void* __restrict__ Ws, const void* __restrict__ Wout,
    const void* __restrict__ bs, const void* __restrict__ bout,
    const int* __restrict__ flags, unsigned short* __restrict__ WT,
    float* __restrict__ biasf, int* __restrict__ bucket_cursor) {
  int f32 = flags[0];
  int gid = blockIdx.x * 256 + threadIdx.x;
  int stride = gridDim.x * 256;

  for (int i = gid; i < 512; i += stride) bucket_cursor[i] = i * BCAP;

  // transpose 4 weight matrices into WT[l][n][k] (bf16)
  for (int i = gid; i < 4 * 4096; i += stride) {
    int l = i >> 12;
    int r = i & 4095;
    int k = r >> 6;
    int nn = r & 63;
    unsigned short v;
    if (l < 3) {
      v = f32 ? f32_to_bf16u(((const float*)Ws)[l * 4096 + r])
              : ((const unsigned short*)Ws)[l * 4096 + r];
    } else {
      v = f32 ? f32_to_bf16u(((const float*)Wout)[r])
              : ((const unsigned short*)Wout)[r];
    }
    WT[l * 4096 + nn * 64 + k] = v;
  }
  // biases -> fp32
  for (int i = gid; i < 4 * 64; i += stride) {
    int l = i >> 6;
    int j = i & 63;
    float v;
    if (l < 3)
      v = f32 ? ((const float*)bs)[l * 64 + j]
              : bf16u_to_f32(((const unsigned short*)bs)[l * 64 + j]);
    else
      v = f32 ? ((const float*)bout)[j]
              : bf16u_to_f32(((const unsigned short*)bout)[j]);
    biasf[i] = v;
  }
}

// ---------------- bucketed partition (fixed-capacity regions) ----------------

__global__ __launch_bounds__(256) void k_partition(
    const void* __restrict__ ei, const int* __restrict__ flags,
    int* __restrict__ bucket_cursor, int* __restrict__ packed, int e) {
  __shared__ int lhist[512];
  __shared__ int lbase[512];
  int tid = threadIdx.x;
  int t0 = blockIdx.x * PTILE;
  int tend = min(t0 + PTILE, e);
  if (t0 >= e) return;
  int i64 = flags[1];

  for (int b = tid; b < 512; b += 256) lhist[b] = 0;
  __syncthreads();

  if (i64) {
    const long long* dst = (const long long*)ei + e;
    for (int i = t0 + tid; i < tend; i += 256)
      atomicAdd(&lhist[((int)dst[i]) >> BSHIFT], 1);
  } else {
    const int* dst = (const int*)ei + e;
    for (int i = t0 + tid; i < tend; i += 256)
      atomicAdd(&lhist[dst[i] >> BSHIFT], 1);
  }
  __syncthreads();

  for (int b = tid; b < 512; b += 256) {
    int c = lhist[b];
    lbase[b] = c ? atomicAdd(&bucket_cursor[b], c) : 0;
    lhist[b] = 0;  // reuse as rank counter
  }
  __syncthreads();

  if (i64) {
    const long long* srcp = (const long long*)ei;
    const long long* dstp = srcp + e;
    for (int i = t0 + tid; i < tend; i += 256) {
      int s = (int)srcp[i];
      int d = (int)dstp[i];
      int b = d >> BSHIFT;
      int r = atomicAdd(&lhist[b], 1);
      packed[lbase[b] + r] = (s << BSHIFT) | (d & (BNODES - 1));
    }
  } else {
    const int* srcp = (const int*)ei;
    const int* dstp = srcp + e;
    for (int i = t0 + tid; i < tend; i += 256) {
      int s = srcp[i];
      int d = dstp[i];
      int b = d >> BSHIFT;
      int r = atomicAdd(&lhist[b], 1);
      packed[lbase[b] + r] = (s << BSHIFT) | (d & (BNODES - 1));
    }
  }
}

// One block per bucket: LDS counting sort -> per-node src list (grouped by
// dst) in the bucket's csr region, rowrange (beg,end), dinv.
__global__ __launch_bounds__(256) void k_sort_csr(
    const int* __restrict__ packed, const int* __restrict__ bucket_cursor,
    int* __restrict__ csr, int2* __restrict__ rowrange,
    float* __restrict__ dinv, int n) {
  __shared__ int lcnt[BNODES];
  __shared__ int lofs[BNODES];
  __shared__ int sbuf[BNODES];
  int tid = threadIdx.x;
  int bucket = blockIdx.x;
  int node0 = bucket << BSHIFT;
  int nodes = min(BNODES, n - node0);
  int s0 = bucket * BCAP;
  int s1 = bucket_cursor[bucket];  // region end after partition
  lcnt[tid] = 0;
  __syncthreads();
  for (int i = s0 + tid; i < s1; i += 256)
    atomicAdd(&lcnt[packed[i] & (BNODES - 1)], 1);
  __syncthreads();
  int v = lcnt[tid];
  sbuf[tid] = v;
  __syncthreads();
  for (int off = 1; off < BNODES; off <<= 1) {
    int tv = (tid >= off) ? sbuf[tid - off] : 0;
    __syncthreads();
    sbuf[tid] += tv;
    __syncthreads();
  }
  int excl = sbuf[tid] - v;
  lofs[tid] = excl;
  lcnt[tid] = 0;  // reuse as rank counter
  if (tid < nodes) {
    rowrange[node0 + tid] = make_int2(s0 + excl, s0 + excl + v);
    dinv[node0 + tid] = rsqrtf((float)(v + 1));  // +1 = self loop
  }
  __syncthreads();
  for (int i = s0 + tid; i < s1; i += 256) {
    int pk = packed[i];
    int ld = pk & (BNODES - 1);
    int r = atomicAdd(&lcnt[ld], 1);
    csr[s0 + lofs[ld] + r] = pk >> BSHIFT;
  }
}

// ---------------- z0 = dinv * x0 (bf16), handles fp32/bf16 input ----------------

__global__ __launch_bounds__(256) void k_scale(
    const void* __restrict__ x0, const int* __restrict__ flags,
    const float* __restrict__ dinv, ushort4* __restrict__ z, int n16) {
  int f32 = flags[0];
  int i = blockIdx.x * 256 + threadIdx.x;
  int stride = gridDim.x * 256;
  for (; i < n16; i += stride) {
    float d = dinv[i >> 4];
    ushort4 o;
    if (f32) {
      float4 v = ((const float4*)x0)[i];
      o.x = f32_to_bf16u(d * v.x);
      o.y = f32_to_bf16u(d * v.y);
      o.z = f32_to_bf16u(d * v.z);
      o.w = f32_to_bf16u(d * v.w);
    } else {
      ushort4 v = ((const ushort4*)x0)[i];
      o.x = f32_to_bf16u(d * bf16u_to_f32(v.x));
      o.y = f32_to_bf16u(d * bf16u_to_f32(v.y));
      o.z = f32_to_bf16u(d * bf16u_to_f32(v.z));
      o.w = f32_to_bf16u(d * bf16u_to_f32(v.w));
    }
    z[i] = o;
  }
}

// ---------------- fused layer ----------------
// y = dinv_dst*(z_dst + sum z_src); out = relu(yW+b) [optionally * dinv].
// Round-5: same body as round-4 (persistent blocks, inter-tile prefetch,
// double-buffered ybf, one barrier/tile), grid 1024 -> 2048.
// Evidence: r4 VGPR=64 (no spill, WRITE_SIZE at the 12.5 MB floor) but
// OccupancyPercent 31% -- the 1024-block grid itself capped residency at
// 4 blocks/CU. At 64 VGPR the HW allows 8 waves/SIMD (pool 2048/SIMD),
// i.e. 8 blocks/CU = 32 waves. Grid 2048 doubles resident waves with a
// byte-identical kernel body. Latency-concurrency theory test: if dur
// doesn't move with occupancy ~2x, pivot to shfl-merge / gather-byte cuts.
// Spill tripwire: WRITE_SIZE must stay ~12.5 MB, VGPR must stay 64.
__global__ __launch_bounds__(256, 4) void k_fused(
    const unsigned short* __restrict__ z, const int2* __restrict__ rowrange,
    const int* __restrict__ csr, const float* __restrict__ dinv,
    const unsigned short* __restrict__ WT, const float* __restrict__ biasf,
    unsigned short* __restrict__ out, int n, int scale_out, int ntiles) {
  __shared__ unsigned short ybf[2][16 * 80];
  const int tid = threadIdx.x;
  const int lane = tid & 63;
  const int w = tid >> 6;   // wave id = output col-tile
  const int q = lane >> 4;  // phase-2 quarter
  const int f = lane & 15;  // phase-2 frag row
  const int h = lane & 7;   // 16B slot within a 128B z row
  const int g8 = lane >> 3; // 8-lane group = edge slot group
  const int jx = lane >> 4; // index-table node
  const int m = lane & 15;  // index-table slot

  // B-frags + bias for this wave's column tile (once per persistent block)
  short8 b0 = *(const short8*)(WT + (size_t)(f + 16 * w) * 64 + q * 8);
  short8 b1 = *(const short8*)(WT + (size_t)(f + 16 * w) * 64 + 32 + q * 8);
  const float bv = biasf[16 * w + f];

  const short8* z8 = (const short8*)z;
  const int NB = gridDim.x;
  if ((int)blockIdx.x >= ntiles) return;

  // decode one rowrange word-vector into ranges/degrees + load the packed
  // index table entry (slot 0 = self, slots 1..15 = first 15 csr edges)
  auto decode = [&](int rrw_v, int bn, int& rx0, int& rx1, int& rx2, int& rx3,
                    int& d0, int& d1, int& d2, int& d3) -> int {
    rx0 = __shfl(rrw_v, 0, 64);
    int ry0 = __shfl(rrw_v, 1, 64);
    rx1 = __shfl(rrw_v, 2, 64);
    int ry1 = __shfl(rrw_v, 3, 64);
    rx2 = __shfl(rrw_v, 4, 64);
    int ry2 = __shfl(rrw_v, 5, 64);
    rx3 = __shfl(rrw_v, 6, 64);
    int ry3 = __shfl(rrw_v, 7, 64);
    d0 = ry0 - rx0;
    d1 = ry1 - rx1;
    d2 = ry2 - rx2;
    d3 = ry3 - rx3;
    int rxj = (jx & 2) ? ((jx & 1) ? rx3 : rx2) : ((jx & 1) ? rx1 : rx0);
    int dgj = (jx & 2) ? ((jx & 1) ? d3 : d2) : ((jx & 1) ? d1 : d0);
    int coff = (m >= 1 && m <= dgj) ? (m - 1) : 0;
    int idxv = csr[rxj + coff];
    if (m == 0) idxv = bn + jx;
    return idxv;
  };

  // prologue: tile blockIdx.x
  int rrw = 0;
  if (lane < 8)
    rrw = ((const int*)rowrange)[((size_t)blockIdx.x * 16 + w * 4) * 2 + lane];
  int rx0, rx1, rx2, rx3, d0, d1, d2, d3;
  int idx = decode(rrw, blockIdx.x * 16 + w * 4, rx0, rx1, rx2, rx3, d0, d1,
                   d2, d3);
  int pp = 0;

  for (int t = blockIdx.x; t < ntiles; t += NB) {
    const int tn = t + NB;
    const int row0 = t * 16;
    const int base_node = row0 + w * 4;

    // prefetch next tile's rowrange (latency hides under gathers)
    int rrw_n = 0;
    if (lane < 8 && tn < ntiles)
      rrw_n = ((const int*)rowrange)[((size_t)tn * 16 + w * 4) * 2 + lane];

    // --- gathers: 8 instrs max, 8 edges each (16B/lane, 8 lanes/row) ---
    short8 g[8];
#pragma unroll
    for (int t8 = 0; t8 < 8; t8++) {
      const int j = t8 >> 1;
      const int hi = t8 & 1;
      int dg = (j == 0) ? d0 : (j == 1) ? d1 : (j == 2) ? d2 : d3;
      if (hi && dg < 8) continue;  // wave-uniform skip
      int u = (hi << 3) + g8;
      int s = __shfl(idx, (j << 4) + u, 64);
      g[t8] = z8[(size_t)s * 8 + h];
    }

    float a0[8] = {0, 0, 0, 0, 0, 0, 0, 0};
    float a1[8] = {0, 0, 0, 0, 0, 0, 0, 0};
    float a2[8] = {0, 0, 0, 0, 0, 0, 0, 0};
    float a3[8] = {0, 0, 0, 0, 0, 0, 0, 0};
#pragma unroll
    for (int t8 = 0; t8 < 8; t8++) {
      const int j = t8 >> 1;
      const int hi = t8 & 1;
      int dg = (j == 0) ? d0 : (j == 1) ? d1 : (j == 2) ? d2 : d3;
      if (hi && dg < 8) continue;
      int u = (hi << 3) + g8;
      float vm = (u <= dg) ? 1.f : 0.f;
      float* aj = (j == 0) ? a0 : (j == 1) ? a1 : (j == 2) ? a2 : a3;
#pragma unroll
      for (int c = 0; c < 8; c++)
        aj[c] += vm * bf16u_to_f32((unsigned short)g[t8][c]);
    }

    // prefetch next tile's index table (csr load hides under merge/phase 2)
    int nrx0 = 0, nrx1 = 0, nrx2 = 0, nrx3 = 0;
    int nd0 = 0, nd1 = 0, nd2 = 0, nd3 = 0, idx_n = 0;
    if (tn < ntiles)
      idx_n = decode(rrw_n, tn * 16 + w * 4, nrx0, nrx1, nrx2, nrx3, nd0, nd1,
                     nd2, nd3);

    // --- rare tail: deg > 15, 8 edges per round ---
#pragma unroll
    for (int j = 0; j < 4; j++) {
      int rx = (j == 0) ? rx0 : (j == 1) ? rx1 : (j == 2) ? rx2 : rx3;
      int dg = (j == 0) ? d0 : (j == 1) ? d1 : (j == 2) ? d2 : d3;
      float* aj = (j == 0) ? a0 : (j == 1) ? a1 : (j == 2) ? a2 : a3;
      for (int e0 = 15; e0 < dg; e0 += 8) {
        int e = e0 + g8;
        bool vv = e < dg;
        int s = csr[rx + (vv ? e : 0)];
        short8 tv = z8[(size_t)s * 8 + h];
        float vm = vv ? 1.f : 0.f;
#pragma unroll
        for (int c = 0; c < 8; c++)
          aj[c] += vm * bf16u_to_f32((unsigned short)tv[c]);
      }
    }

    // --- merge the 8 groups (butterfly over lane bits 3,4,5) ---
#pragma unroll
    for (int c = 0; c < 8; c++) {
      a0[c] += __shfl_xor(a0[c], 8, 64);
      a1[c] += __shfl_xor(a1[c], 8, 64);
      a2[c] += __shfl_xor(a2[c], 8, 64);
      a3[c] += __shfl_xor(a3[c], 8, 64);
      a0[c] += __shfl_xor(a0[c], 16, 64);
      a1[c] += __shfl_xor(a1[c], 16, 64);
      a2[c] += __shfl_xor(a2[c], 16, 64);
      a3[c] += __shfl_xor(a3[c], 16, 64);
      a0[c] += __shfl_xor(a0[c], 32, 64);
      a1[c] += __shfl_xor(a1[c], 32, 64);
      a2[c] += __shfl_xor(a2[c], 32, 64);
      a3[c] += __shfl_xor(a3[c], 32, 64);
    }

    // --- lanes 0..31: scale by dinv_dst, pack, write y rows (16B each) ---
    if (lane < 32) {
      int jw = lane >> 3;  // node within wave
      float dv = dinv[base_node + jw];
      unsigned int pk[4];
#pragma unroll
      for (int cp = 0; cp < 4; cp++) {
        float vlo = (jw & 2) ? ((jw & 1) ? a3[2 * cp] : a2[2 * cp])
                             : ((jw & 1) ? a1[2 * cp] : a0[2 * cp]);
        float vhi = (jw & 2) ? ((jw & 1) ? a3[2 * cp + 1] : a2[2 * cp + 1])
                             : ((jw & 1) ? a1[2 * cp + 1] : a0[2 * cp + 1]);
        unsigned int lo = f32_to_bf16u(dv * vlo);
        unsigned int hi = f32_to_bf16u(dv * vhi);
        pk[cp] = lo | (hi << 16);
      }
      *(uint4*)&ybf[pp][(w * 4 + jw) * 80 + 8 * h] =
          make_uint4(pk[0], pk[1], pk[2], pk[3]);
    }
    __syncthreads();

    // --- phase 2: MFMA yW for this wave's 16 columns ---
    short8 fa0 = *(const short8*)&ybf[pp][f * 80 + q * 8];
    short8 fa1 = *(const short8*)&ybf[pp][f * 80 + 32 + q * 8];
    float4v zz = {0.f, 0.f, 0.f, 0.f};
    float4v acc = __builtin_amdgcn_mfma_f32_16x16x32_bf16(fa0, b0, zz, 0, 0, 0);
    acc = __builtin_amdgcn_mfma_f32_16x16x32_bf16(fa1, b1, acc, 0, 0, 0);

    if (scale_out) {
      float4 dv4 = *(const float4*)(dinv + row0 + q * 4);
      float dvr[4] = {dv4.x, dv4.y, dv4.z, dv4.w};
#pragma unroll
      for (int reg = 0; reg < 4; reg++) {
        int row = row0 + q * 4 + reg;
        if (row < n)
          out[(size_t)row * 64 + 16 * w + f] =
              f32_to_bf16u(dvr[reg] * fmaxf(acc[reg] + bv, 0.f));
      }
    } else {
#pragma unroll
      for (int reg = 0; reg < 4; reg++) {
        int row = row0 + q * 4 + reg;
        if (row < n)
          out[(size_t)row * 64 + 16 * w + f] =
              f32_to_bf16u(fmaxf(acc[reg] + bv, 0.f));
      }
    }

    // rotate pipeline state
    rx0 = nrx0; rx1 = nrx1; rx2 = nrx2; rx3 = nrx3;
    d0 = nd0; d1 = nd1; d2 = nd2; d3 = nd3;
    idx = idx_n;
    pp ^= 1;
  }
}

// ---------------- final projection GEMM ----------------
// out[N,64] = x @ Wout + bias; x bf16; store dtype per flags[0].
__global__ __launch_bounds__(256) void k_gemm_final(
    const unsigned short* __restrict__ xin,
    const unsigned short* __restrict__ WT, const float* __restrict__ bias,
    void* __restrict__ out, const int* __restrict__ flags, int ntiles) {
  int lane = threadIdx.x & 63;
  int wid = threadIdx.x >> 6;
  int f = lane & 15;
  int q = lane >> 4;

  short8 bfr[4][2];
#pragma unroll
  for (int ct = 0; ct < 4; ct++)
#pragma unroll
    for (int kt = 0; kt < 2; kt++)
      bfr[ct][kt] =
          *(const short8*)(WT + (size_t)(f + 16 * ct) * 64 + kt * 32 + q * 8);

  int wave = blockIdx.x * 4 + wid;
  int nwaves = gridDim.x * 4;
  for (int t = wave; t < ntiles; t += nwaves) {
    int row0 = t * 16;
    const unsigned short* xr = xin + (size_t)(row0 + f) * 64 + q * 8;
    short8 a0 = *(const short8*)(xr);
    short8 a1 = *(const short8*)(xr + 32);
    float4v acc[4];
#pragma unroll
    for (int ct = 0; ct < 4; ct++) {
      float4v z = {0.f, 0.f, 0.f, 0.f};
      acc[ct] =
          __builtin_amdgcn_mfma_f32_16x16x32_bf16(a0, bfr[ct][0], z, 0, 0, 0);
      acc[ct] = __builtin_amdgcn_mfma_f32_16x16x32_bf16(a1, bfr[ct][1],
                                                        acc[ct], 0, 0, 0);
    }
    int f32o = flags[0];
    float bv[4];
#pragma unroll
    for (int ct = 0; ct < 4; ct++) bv[ct] = bias[f + 16 * ct];
    if (f32o) {
      float* op = (float*)out;
#pragma unroll
      for (int reg = 0; reg < 4; reg++) {
        size_t rb = (size_t)(row0 + q * 4 + reg) * 64 + f;
#pragma unroll
        for (int ct = 0; ct < 4; ct++) op[rb + 16 * ct] = acc[ct][reg] + bv[ct];
      }
    } else {
      unsigned short* op = (unsigned short*)out;
#pragma unroll
      for (int reg = 0; reg < 4; reg++) {
        size_t rb = (size_t)(row0 + q * 4 + reg) * 64 + f;
#pragma unroll
        for (int ct = 0; ct < 4; ct++)
          op[rb + 16 * ct] = f32_to_bf16u(acc[ct][reg] + bv[ct]);
      }
    }
  }
}

// ---------------- launch ----------------

extern "C" void kernel_launch(void* const* d_in, const int* in_sizes, int n_in,
                              void* d_out, int out_size, void* d_ws,
                              size_t ws_size, hipStream_t stream) {
  const void* x0 = d_in[0];
  const void* ei = d_in[1];
  const void* Ws = d_in[2];
  const void* bs = d_in[3];
  const void* Wout = d_in[4];
  const void* bout = d_in[5];

  const int N = in_sizes[0] / D;  // 100000
  const int E = in_sizes[1] / 2;  // 1000000
  const int NBUC = (N + BNODES - 1) >> BSHIFT;  // 391
  const int NT = (N + 15) / 16;  // 6250 row tiles

  char* p = (char*)d_ws;
  auto alloc = [&](size_t bytes) {
    char* r = p;
    p += (bytes + 511) & ~(size_t)511;
    return r;
  };
  int* flags = (int*)alloc(8);
  int* bucket_cursor = (int*)alloc(512 * 4);
  int* packed = (int*)alloc((size_t)512 * BCAP * 4);
  int* csr = (int*)alloc((size_t)512 * BCAP * 4);
  int2* rowrange = (int2*)alloc((size_t)N * 8);
  float* dinv = (float*)alloc((size_t)N * 4);
  unsigned short* WT = (unsigned short*)alloc(4 * 4096 * 2);
  float* biasf = (float*)alloc(4 * 64 * 4);
  unsigned short* za = (unsigned short*)alloc((size_t)N * D * 2);
  unsigned short* zb = (unsigned short*)alloc((size_t)N * D * 2);
  (void)ws_size;
  (void)n_in;
  (void)out_size;

  k_probe<<<1, 64, 0, stream>>>(Ws, ei, flags);
  k_prep<<<32, 256, 0, stream>>>(Ws, Wout, bs, bout, flags, WT, biasf,
                                 bucket_cursor);
  int ptiles = (E + PTILE - 1) / PTILE;
  k_partition<<<ptiles, 256, 0, stream>>>(ei, flags, bucket_cursor, packed, E);
  k_sort_csr<<<NBUC, 256, 0, stream>>>(packed, bucket_cursor, csr, rowrange,
                                       dinv, N);
  k_scale<<<1024, 256, 0, stream>>>(x0, flags, dinv, (ushort4*)za, N * 16);

  const int FGRID = 2048;  // 8 persistent blocks per CU (VGPR=64 fits 32 waves)
  // layer 0: za -> zb (z'), layer 1: zb -> za (z'), layer 2: za -> zb (x3)
  k_fused<<<FGRID, 256, 0, stream>>>(za, rowrange, csr, dinv, WT + 0 * 4096,
                                     biasf + 0 * 64, zb, N, 1, NT);
  k_fused<<<FGRID, 256, 0, stream>>>(zb, rowrange, csr, dinv, WT + 1 * 4096,
                                     biasf + 1 * 64, za, N, 1, NT);
  k_fused<<<FGRID, 256, 0, stream>>>(za, rowrange, csr, dinv, WT + 2 * 4096,
                                     biasf + 2 * 64, zb, N, 0, NT);
  k_gemm_final<<<(NT + 3) / 4, 256, 0, stream>>>(zb, WT + 3 * 4096,
                                                 biasf + 3 * 64, d_out, flags,
                                                 NT);
}

// Round 6
// 228.104 us; speedup vs baseline: 1.1490x; 1.1355x over previous
//
#include <hip/hip_runtime.h>
#include <hip/hip_bf16.h>

#define D 64
#define BSHIFT 8           // 256 nodes per bucket
#define BNODES 256
#define BCAP 4096          // edge capacity per bucket region (exp 2558, +30 sigma)
#define PTILE 2048         // edges per partition tile (489 blocks -> full CU coverage)

typedef __attribute__((ext_vector_type(8))) short short8;
typedef __attribute__((ext_vector_type(4))) float float4v;

// flags[0] = 1 if float tensors are fp32 (else bf16)
// flags[1] = 1 if edge_index is int64 (else int32)

__device__ __forceinline__ float bf16u_to_f32(unsigned short u) {
  union { unsigned int i; float f; } c;
  c.i = ((unsigned int)u) << 16;
  return c.f;
}

__device__ __forceinline__ unsigned short f32_to_bf16u(float f) {
  union { float f; unsigned int u; } c;
  c.f = f;
  unsigned int r = (c.u + 0x7fffu + ((c.u >> 16) & 1u)) >> 16;  // RNE
  return (unsigned short)r;
}

// ---------------- probe dtypes ----------------

__global__ void k_probe(const void* W, const void* ei, int* flags) {
  int lane = threadIdx.x & 63;
  const unsigned short* wb = (const unsigned short*)W;
  bool big = false;
  for (int i = lane; i < 512; i += 64) {
    float v = bf16u_to_f32(wb[i]);
    if (!(fabsf(v) < 100.f)) big = true;  // NaN lands here too
  }
  int anybig = __any(big);
  const int* e32 = (const int*)ei;
  bool nz = (e32[2 * lane + 1] != 0);  // odd words of first 64 pairs
  int anynz = __any(nz);
  if (threadIdx.x == 0) {
    flags[0] = anybig ? 1 : 0;  // huge magnitudes => data is actually fp32
    flags[1] = anynz ? 0 : 1;   // all-zero odd words => int64
  }
}

// ---------------- weight prep + cursor init (parallel) ----------------

__global__ __launch_bounds__(256) void k_prep(
    const void* __restrict__ Ws, const void* __restrict__ Wout,
    const void* __restrict__ bs, const void* __restrict__ bout,
    const int* __restrict__ flags, unsigned short* __restrict__ WT,
    float* __restrict__ biasf, int* __restrict__ bucket_cursor) {
  int f32 = flags[0];
  int gid = blockIdx.x * 256 + threadIdx.x;
  int stride = gridDim.x * 256;

  for (int i = gid; i < 512; i += stride) bucket_cursor[i] = i * BCAP;

  // transpose 4 weight matrices into WT[l][n][k] (bf16)
  for (int i = gid; i < 4 * 4096; i += stride) {
    int l = i >> 12;
    int r = i & 4095;
    int k = r >> 6;
    int nn = r & 63;
    unsigned short v;
    if (l < 3) {
      v = f32 ? f32_to_bf16u(((const float*)Ws)[l * 4096 + r])
              : ((const unsigned short*)Ws)[l * 4096 + r];
    } else {
      v = f32 ? f32_to_bf16u(((const float*)Wout)[r])
              : ((const unsigned short*)Wout)[r];
    }
    WT[l * 4096 + nn * 64 + k] = v;
  }
  // biases -> fp32
  for (int i = gid; i < 4 * 64; i += stride) {
    int l = i >> 6;
    int j = i & 63;
    float v;
    if (l < 3)
      v = f32 ? ((const float*)bs)[l * 64 + j]
              : bf16u_to_f32(((const unsigned short*)bs)[l * 64 + j]);
    else
      v = f32 ? ((const float*)bout)[j]
              : bf16u_to_f32(((const unsigned short*)bout)[j]);
    biasf[i] = v;
  }
}

// ---------------- bucketed partition (fixed-capacity regions) ----------------

__global__ __launch_bounds__(256) void k_partition(
    const void* __restrict__ ei, const int* __restrict__ flags,
    int* __restrict__ bucket_cursor, int* __restrict__ packed, int e) {
  __shared__ int lhist[512];
  __shared__ int lbase[512];
  int tid = threadIdx.x;
  int t0 = blockIdx.x * PTILE;
  int tend = min(t0 + PTILE, e);
  if (t0 >= e) return;
  int i64 = flags[1];

  for (int b = tid; b < 512; b += 256) lhist[b] = 0;
  __syncthreads();

  if (i64) {
    const long long* dst = (const long long*)ei + e;
    for (int i = t0 + tid; i < tend; i += 256)
      atomicAdd(&lhist[((int)dst[i]) >> BSHIFT], 1);
  } else {
    const int* dst = (const int*)ei + e;
    for (int i = t0 + tid; i < tend; i += 256)
      atomicAdd(&lhist[dst[i] >> BSHIFT], 1);
  }
  __syncthreads();

  for (int b = tid; b < 512; b += 256) {
    int c = lhist[b];
    lbase[b] = c ? atomicAdd(&bucket_cursor[b], c) : 0;
    lhist[b] = 0;  // reuse as rank counter
  }
  __syncthreads();

  if (i64) {
    const long long* srcp = (const long long*)ei;
    const long long* dstp = srcp + e;
    for (int i = t0 + tid; i < tend; i += 256) {
      int s = (int)srcp[i];
      int d = (int)dstp[i];
      int b = d >> BSHIFT;
      int r = atomicAdd(&lhist[b], 1);
      packed[lbase[b] + r] = (s << BSHIFT) | (d & (BNODES - 1));
    }
  } else {
    const int* srcp = (const int*)ei;
    const int* dstp = srcp + e;
    for (int i = t0 + tid; i < tend; i += 256) {
      int s = srcp[i];
      int d = dstp[i];
      int b = d >> BSHIFT;
      int r = atomicAdd(&lhist[b], 1);
      packed[lbase[b] + r] = (s << BSHIFT) | (d & (BNODES - 1));
    }
  }
}

// One block per bucket: LDS counting sort -> per-node src list (grouped by
// dst) in the bucket's csr region, rowrange (beg,end), dinv.
__global__ __launch_bounds__(256) void k_sort_csr(
    const int* __restrict__ packed, const int* __restrict__ bucket_cursor,
    int* __restrict__ csr, int2* __restrict__ rowrange,
    float* __restrict__ dinv, int n) {
  __shared__ int lcnt[BNODES];
  __shared__ int lofs[BNODES];
  __shared__ int sbuf[BNODES];
  int tid = threadIdx.x;
  int bucket = blockIdx.x;
  int node0 = bucket << BSHIFT;
  int nodes = min(BNODES, n - node0);
  int s0 = bucket * BCAP;
  int s1 = bucket_cursor[bucket];  // region end after partition
  lcnt[tid] = 0;
  __syncthreads();
  for (int i = s0 + tid; i < s1; i += 256)
    atomicAdd(&lcnt[packed[i] & (BNODES - 1)], 1);
  __syncthreads();
  int v = lcnt[tid];
  sbuf[tid] = v;
  __syncthreads();
  for (int off = 1; off < BNODES; off <<= 1) {
    int tv = (tid >= off) ? sbuf[tid - off] : 0;
    __syncthreads();
    sbuf[tid] += tv;
    __syncthreads();
  }
  int excl = sbuf[tid] - v;
  lofs[tid] = excl;
  lcnt[tid] = 0;  // reuse as rank counter
  if (tid < nodes) {
    rowrange[node0 + tid] = make_int2(s0 + excl, s0 + excl + v);
    dinv[node0 + tid] = rsqrtf((float)(v + 1));  // +1 = self loop
  }
  __syncthreads();
  for (int i = s0 + tid; i < s1; i += 256) {
    int pk = packed[i];
    int ld = pk & (BNODES - 1);
    int r = atomicAdd(&lcnt[ld], 1);
    csr[s0 + lofs[ld] + r] = pk >> BSHIFT;
  }
}

// ---------------- z0 = dinv * x0 (bf16), handles fp32/bf16 input ----------------

__global__ __launch_bounds__(256) void k_scale(
    const void* __restrict__ x0, const int* __restrict__ flags,
    const float* __restrict__ dinv, ushort4* __restrict__ z, int n16) {
  int f32 = flags[0];
  int i = blockIdx.x * 256 + threadIdx.x;
  int stride = gridDim.x * 256;
  for (; i < n16; i += stride) {
    float d = dinv[i >> 4];
    ushort4 o;
    if (f32) {
      float4 v = ((const float4*)x0)[i];
      o.x = f32_to_bf16u(d * v.x);
      o.y = f32_to_bf16u(d * v.y);
      o.z = f32_to_bf16u(d * v.z);
      o.w = f32_to_bf16u(d * v.w);
    } else {
      ushort4 v = ((const ushort4*)x0)[i];
      o.x = f32_to_bf16u(d * bf16u_to_f32(v.x));
      o.y = f32_to_bf16u(d * bf16u_to_f32(v.y));
      o.z = f32_to_bf16u(d * bf16u_to_f32(v.z));
      o.w = f32_to_bf16u(d * bf16u_to_f32(v.w));
    }
    z[i] = o;
  }
}

// ---------------- fused layer ----------------
// y = dinv_dst*(z_dst + sum z_src); out = relu(yW+b) [optionally * dinv].
// One block per 16-node tile (r3 structure -- persistent/occupancy variants
// r1/r4/r5 all regressed: resident-wave count is NOT the limiter).
// Round-6 change: merge via LDS partials instead of the 96-shfl butterfly.
//   old: 3-level shfl_xor over 8 groups = 96 ds_bpermute + 96 adds, a
//        dependent ~450cy chain between gather-return and the barrier.
//   new: each lane writes its 32 partial f32 (4 nodes x 8ch) as 8x float4
//        to a per-wave XOR-swizzled LDS region part[j][g][ch] (granule
//        index gi^g -> 8-way=optimal banking for both writes and reads),
//        then reads 8x float4 for its (node jr=lane>>4, ch 4*gr..) slice
//        and sums: 16 DS ops + 28 adds, uniform (no divergent pack).
//   Wave-synchronous (per-wave buffer, lgkmcnt ordering, no barrier).
// LDS: 32KB partials + 2.5KB ybf -> 4 blocks/CU (= r3's measured effective
// residency; r5 proved extra waves don't pay). Spill tripwire: WRITE_SIZE
// ~12.5MB. Bank tripwire: SQ_LDS_BANK_CONFLICT ~0.
__global__ __launch_bounds__(256, 4) void k_fused(
    const unsigned short* __restrict__ z, const int2* __restrict__ rowrange,
    const int* __restrict__ csr, const float* __restrict__ dinv,
    const unsigned short* __restrict__ WT, const float* __restrict__ biasf,
    unsigned short* __restrict__ out, int n, int scale_out) {
  __shared__ __align__(16) float part[4 * 2048];  // [wave][node][group][ch]
  __shared__ unsigned short ybf[16 * 80];
  int tid = threadIdx.x;
  int lane = tid & 63;
  int w = tid >> 6;   // wave id = output col-tile
  int q = lane >> 4;  // phase-2 quarter
  int f = lane & 15;  // phase-2 frag row
  int h = lane & 7;   // 16B slot within a 128B z row
  int g8 = lane >> 3; // 8-lane group = edge slot group

  // B-frags for this wave's column tile
  short8 b0 = *(const short8*)(WT + (size_t)(f + 16 * w) * 64 + q * 8);
  short8 b1 = *(const short8*)(WT + (size_t)(f + 16 * w) * 64 + 32 + q * 8);

  int row0 = blockIdx.x * 16;
  int base_node = row0 + w * 4;
  const short8* z8 = (const short8*)z;

  // --- rowrange: one 8-lane load, broadcast via shfl ---
  int rrw = 0;
  if (lane < 8) rrw = ((const int*)rowrange)[(size_t)base_node * 2 + lane];
  int rx0 = __shfl(rrw, 0, 64);
  int ry0 = __shfl(rrw, 1, 64);
  int rx1 = __shfl(rrw, 2, 64);
  int ry1 = __shfl(rrw, 3, 64);
  int rx2 = __shfl(rrw, 4, 64);
  int ry2 = __shfl(rrw, 5, 64);
  int rx3 = __shfl(rrw, 6, 64);
  int ry3 = __shfl(rrw, 7, 64);
  int deg0 = ry0 - rx0;
  int deg1 = ry1 - rx1;
  int deg2 = ry2 - rx2;
  int deg3 = ry3 - rx3;

  // --- index table: lane (jx*16+m) holds slot m of node jx ---
  // slot 0 = self, slots 1..15 = first 15 csr edges (clamped dups if short)
  int jx = lane >> 4;
  int m = lane & 15;
  int rxj = (jx & 2) ? ((jx & 1) ? rx3 : rx2) : ((jx & 1) ? rx1 : rx0);
  int dgj = (jx & 2) ? ((jx & 1) ? deg3 : deg2) : ((jx & 1) ? deg1 : deg0);
  int coff = (m >= 1 && m <= dgj) ? (m - 1) : 0;
  int idx = csr[rxj + coff];
  if (m == 0) idx = base_node + jx;

  // --- phase 1: 8 gather instrs, 8 edges each (16B/lane, 8 lanes/row) ---
  float a0[8] = {0, 0, 0, 0, 0, 0, 0, 0};
  float a1[8] = {0, 0, 0, 0, 0, 0, 0, 0};
  float a2[8] = {0, 0, 0, 0, 0, 0, 0, 0};
  float a3[8] = {0, 0, 0, 0, 0, 0, 0, 0};

  short8 g[8];
#pragma unroll
  for (int t = 0; t < 8; t++) {
    int u = ((t & 1) << 3) + g8;                 // slot 0..15
    int sl = ((t >> 1) << 4) + u;                // table holder lane
    int s = __shfl(idx, sl, 64);
    g[t] = z8[(size_t)s * 8 + h];
  }
#pragma unroll
  for (int t = 0; t < 8; t++) {
    int u = ((t & 1) << 3) + g8;
    const int j = t >> 1;
    int dg = (j == 0) ? deg0 : (j == 1) ? deg1 : (j == 2) ? deg2 : deg3;
    float vm = (u <= dg) ? 1.f : 0.f;
    float* aj = (j == 0) ? a0 : (j == 1) ? a1 : (j == 2) ? a2 : a3;
#pragma unroll
    for (int c = 0; c < 8; c++)
      aj[c] += vm * bf16u_to_f32((unsigned short)g[t][c]);
  }

  // --- rare tail: deg > 15, 8 edges per round ---
#pragma unroll
  for (int j = 0; j < 4; j++) {
    int rx = (j == 0) ? rx0 : (j == 1) ? rx1 : (j == 2) ? rx2 : rx3;
    int dg = (j == 0) ? deg0 : (j == 1) ? deg1 : (j == 2) ? deg2 : deg3;
    float* aj = (j == 0) ? a0 : (j == 1) ? a1 : (j == 2) ? a2 : a3;
    for (int e0 = 15; e0 < dg; e0 += 8) {
      int e = e0 + g8;
      bool vv = e < dg;
      int s = csr[rx + (vv ? e : 0)];
      short8 tv = z8[(size_t)s * 8 + h];
      float vm = vv ? 1.f : 0.f;
#pragma unroll
      for (int c = 0; c < 8; c++)
        aj[c] += vm * bf16u_to_f32((unsigned short)tv[c]);
    }
  }

  // --- merge the 8 groups via per-wave XOR-swizzled LDS partials ---
  // layout: byte = w*8192 + j*2048 + g*256 + ((gi ^ g) << 4), gi = ch>>2
  char* pb = (char*)part + (w << 13);
  {
    int base_wg = g8 << 8;  // g8*256
#pragma unroll
    for (int j = 0; j < 4; j++) {
      const float* aj = (j == 0) ? a0 : (j == 1) ? a1 : (j == 2) ? a2 : a3;
      int jb = j << 11;
      *(float4*)(pb + jb + base_wg + ((((2 * h) ^ g8)) << 4)) =
          make_float4(aj[0], aj[1], aj[2], aj[3]);
      *(float4*)(pb + jb + base_wg + ((((2 * h + 1) ^ g8)) << 4)) =
          make_float4(aj[4], aj[5], aj[6], aj[7]);
    }
  }
  // read back: lane -> node jr = lane>>4, channels 4*gr..4*gr+3 (gr=lane&15)
  int jr = lane >> 4;
  int gr = lane & 15;
  float s0 = 0.f, s1 = 0.f, s2 = 0.f, s3 = 0.f;
#pragma unroll
  for (int gg = 0; gg < 8; gg++) {
    float4 v = *(const float4*)(pb + (jr << 11) + (gg << 8) + ((gr ^ gg) << 4));
    s0 += v.x;
    s1 += v.y;
    s2 += v.z;
    s3 += v.w;
  }
  {
    float dv = dinv[base_node + jr];
    unsigned int w0 = (unsigned int)f32_to_bf16u(dv * s0) |
                      ((unsigned int)f32_to_bf16u(dv * s1) << 16);
    unsigned int w1 = (unsigned int)f32_to_bf16u(dv * s2) |
                      ((unsigned int)f32_to_bf16u(dv * s3) << 16);
    *(uint2*)&ybf[(w * 4 + jr) * 80 + 4 * gr] = make_uint2(w0, w1);
  }
  __syncthreads();

  // --- phase 2: MFMA yW for this wave's 16 columns ---
  short8 fa0 = *(const short8*)&ybf[f * 80 + q * 8];
  short8 fa1 = *(const short8*)&ybf[f * 80 + 32 + q * 8];
  float4v zz = {0.f, 0.f, 0.f, 0.f};
  float4v acc = __builtin_amdgcn_mfma_f32_16x16x32_bf16(fa0, b0, zz, 0, 0, 0);
  acc = __builtin_amdgcn_mfma_f32_16x16x32_bf16(fa1, b1, acc, 0, 0, 0);

  float bv = biasf[16 * w + f];
  if (scale_out) {
    float4 dv4 = *(const float4*)(dinv + row0 + q * 4);
    float d[4] = {dv4.x, dv4.y, dv4.z, dv4.w};
#pragma unroll
    for (int reg = 0; reg < 4; reg++) {
      int row = row0 + q * 4 + reg;
      if (row < n)
        out[(size_t)row * 64 + 16 * w + f] =
            f32_to_bf16u(d[reg] * fmaxf(acc[reg] + bv, 0.f));
    }
  } else {
#pragma unroll
    for (int reg = 0; reg < 4; reg++) {
      int row = row0 + q * 4 + reg;
      if (row < n)
        out[(size_t)row * 64 + 16 * w + f] =
            f32_to_bf16u(fmaxf(acc[reg] + bv, 0.f));
    }
  }
}

// ---------------- final projection GEMM ----------------
// out[N,64] = x @ Wout + bias; x bf16; store dtype per flags[0].
__global__ __launch_bounds__(256) void k_gemm_final(
    const unsigned short* __restrict__ xin,
    const unsigned short* __restrict__ WT, const float* __restrict__ bias,
    void* __restrict__ out, const int* __restrict__ flags, int ntiles) {
  int lane = threadIdx.x & 63;
  int wid = threadIdx.x >> 6;
  int f = lane & 15;
  int q = lane >> 4;

  short8 bfr[4][2];
#pragma unroll
  for (int ct = 0; ct < 4; ct++)
#pragma unroll
    for (int kt = 0; kt < 2; kt++)
      bfr[ct][kt] =
          *(const short8*)(WT + (size_t)(f + 16 * ct) * 64 + kt * 32 + q * 8);

  int wave = blockIdx.x * 4 + wid;
  int nwaves = gridDim.x * 4;
  for (int t = wave; t < ntiles; t += nwaves) {
    int row0 = t * 16;
    const unsigned short* xr = xin + (size_t)(row0 + f) * 64 + q * 8;
    short8 a0 = *(const short8*)(xr);
    short8 a1 = *(const short8*)(xr + 32);
    float4v acc[4];
#pragma unroll
    for (int ct = 0; ct < 4; ct++) {
      float4v z = {0.f, 0.f, 0.f, 0.f};
      acc[ct] =
          __builtin_amdgcn_mfma_f32_16x16x32_bf16(a0, bfr[ct][0], z, 0, 0, 0);
      acc[ct] = __builtin_amdgcn_mfma_f32_16x16x32_bf16(a1, bfr[ct][1],
                                                        acc[ct], 0, 0, 0);
    }
    int f32o = flags[0];
    float bv[4];
#pragma unroll
    for (int ct = 0; ct < 4; ct++) bv[ct] = bias[f + 16 * ct];
    if (f32o) {
      float* op = (float*)out;
#pragma unroll
      for (int reg = 0; reg < 4; reg++) {
        size_t rb = (size_t)(row0 + q * 4 + reg) * 64 + f;
#pragma unroll
        for (int ct = 0; ct < 4; ct++) op[rb + 16 * ct] = acc[ct][reg] + bv[ct];
      }
    } else {
      unsigned short* op = (unsigned short*)out;
#pragma unroll
      for (int reg = 0; reg < 4; reg++) {
        size_t rb = (size_t)(row0 + q * 4 + reg) * 64 + f;
#pragma unroll
        for (int ct = 0; ct < 4; ct++)
          op[rb + 16 * ct] = f32_to_bf16u(acc[ct][reg] + bv[ct]);
      }
    }
  }
}

// ---------------- launch ----------------

extern "C" void kernel_launch(void* const* d_in, const int* in_sizes, int n_in,
                              void* d_out, int out_size, void* d_ws,
                              size_t ws_size, hipStream_t stream) {
  const void* x0 = d_in[0];
  const void* ei = d_in[1];
  const void* Ws = d_in[2];
  const void* bs = d_in[3];
  const void* Wout = d_in[4];
  const void* bout = d_in[5];

  const int N = in_sizes[0] / D;  // 100000
  const int E = in_sizes[1] / 2;  // 1000000
  const int NBUC = (N + BNODES - 1) >> BSHIFT;  // 391
  const int NT = (N + 15) / 16;  // 6250 row tiles

  char* p = (char*)d_ws;
  auto alloc = [&](size_t bytes) {
    char* r = p;
    p += (bytes + 511) & ~(size_t)511;
    return r;
  };
  int* flags = (int*)alloc(8);
  int* bucket_cursor = (int*)alloc(512 * 4);
  int* packed = (int*)alloc((size_t)512 * BCAP * 4);
  int* csr = (int*)alloc((size_t)512 * BCAP * 4);
  int2* rowrange = (int2*)alloc((size_t)N * 8);
  float* dinv = (float*)alloc((size_t)N * 4);
  unsigned short* WT = (unsigned short*)alloc(4 * 4096 * 2);
  float* biasf = (float*)alloc(4 * 64 * 4);
  unsigned short* za = (unsigned short*)alloc((size_t)N * D * 2);
  unsigned short* zb = (unsigned short*)alloc((size_t)N * D * 2);
  (void)ws_size;
  (void)n_in;
  (void)out_size;

  k_probe<<<1, 64, 0, stream>>>(Ws, ei, flags);
  k_prep<<<32, 256, 0, stream>>>(Ws, Wout, bs, bout, flags, WT, biasf,
                                 bucket_cursor);
  int ptiles = (E + PTILE - 1) / PTILE;
  k_partition<<<ptiles, 256, 0, stream>>>(ei, flags, bucket_cursor, packed, E);
  k_sort_csr<<<NBUC, 256, 0, stream>>>(packed, bucket_cursor, csr, rowrange,
                                       dinv, N);
  k_scale<<<1024, 256, 0, stream>>>(x0, flags, dinv, (ushort4*)za, N * 16);

  // layer 0: za -> zb (z'), layer 1: zb -> za (z'), layer 2: za -> zb (x3)
  k_fused<<<NT, 256, 0, stream>>>(za, rowrange, csr, dinv, WT + 0 * 4096,
                                  biasf + 0 * 64, zb, N, 1);
  k_fused<<<NT, 256, 0, stream>>>(zb, rowrange, csr, dinv, WT + 1 * 4096,
                                  biasf + 1 * 64, za, N, 1);
  k_fused<<<NT, 256, 0, stream>>>(za, rowrange, csr, dinv, WT + 2 * 4096,
                                  biasf + 2 * 64, zb, N, 0);
  k_gemm_final<<<(NT + 3) / 4, 256, 0, stream>>>(zb, WT + 3 * 4096,
                                                 biasf + 3 * 64, d_out, flags,
                                                 NT);
}